// Round 1
// baseline (493.210 us; speedup 1.0000x reference)
//
#include <hip/hip_runtime.h>
#include <hip/hip_bf16.h>
#include <stdint.h>

// Problem dims (fixed by harness)
#define Bb 256
#define Nn 196
#define Dd 384
#define Hh 1536
#define NPAD 224      // patch-dim K padded to 7*32 for MFMA
#define MPAD 256      // Wq row pad to 2*128 tiles
#define TTOT (Bb*Nn)  // 50176 tokens
#define TCHUNK 12544  // TTOT/4
#define NCHUNK 4

typedef __attribute__((ext_vector_type(8))) __bf16 bf16x8;
typedef __attribute__((ext_vector_type(4))) float f32x4;

__device__ __forceinline__ ushort f2bf(float f){
  union { float f; unsigned u; } v; v.f = f;
  unsigned r = v.u + 0x7FFFu + ((v.u >> 16) & 1u);   // RNE f32->bf16
  return (ushort)(r >> 16);
}

// ---------- absmax reduction over a weight tensor ----------
__global__ void absmax_k(const float* __restrict__ w, int n, unsigned* __restrict__ out){
  float m = 0.f;
  for (int i = blockIdx.x*blockDim.x + threadIdx.x; i < n; i += gridDim.x*blockDim.x)
    m = fmaxf(m, fabsf(w[i]));
  #pragma unroll
  for (int o = 32; o >= 1; o >>= 1) m = fmaxf(m, __shfl_xor(m, o));
  __shared__ float sm[4];
  if ((threadIdx.x & 63) == 0) sm[threadIdx.x >> 6] = m;
  __syncthreads();
  if (threadIdx.x == 0){
    float mm = fmaxf(fmaxf(sm[0], sm[1]), fmaxf(sm[2], sm[3]));
    atomicMax(out, __float_as_uint(mm));   // floats >=0: uint order == float order
  }
}

// ---------- fake-quant W_attn into zero-padded bf16 [MPAD][NPAD] ----------
__global__ void quant_attn_k(const float* __restrict__ W, const unsigned* __restrict__ amax,
                             const int* __restrict__ bitsp, ushort* __restrict__ Wq){
  int idx = blockIdx.x*256 + threadIdx.x;      // grid covers MPAD*NPAD exactly
  int m = idx / NPAD, n = idx - m*NPAD;
  float qmax = (float)((1 << (bitsp[0]-1)) - 1);
  float s = fmaxf(__uint_as_float(amax[0]) / qmax, 1e-8f);
  float v = 0.f;
  if (m < Nn && n < Nn){
    float q = fminf(fmaxf(rintf(W[m*Nn + n] / s), -qmax), qmax);  // rintf = RNE like jnp.round
    v = q * s;
  }
  Wq[idx] = f2bf(v);
}

// ---------- fake-quant a row-major weight to bf16 (same layout) ----------
__global__ void quant_k(const float* __restrict__ W, int n, const unsigned* __restrict__ amax,
                        const int* __restrict__ bitsp, ushort* __restrict__ Wq){
  int idx = blockIdx.x*256 + threadIdx.x;
  if (idx >= n) return;
  float qmax = (float)((1 << (bitsp[0]-1)) - 1);
  float s = fmaxf(__uint_as_float(amax[0]) / qmax, 1e-8f);
  float q = fminf(fmaxf(rintf(W[idx] / s), -qmax), qmax);
  Wq[idx] = f2bf(q * s);
}

// ---------- norm1 + transpose: hn1T[b][d][n] = bf16(alpha1[d]*x[b][n][d]+beta1[d]); n>=196 -> 0
__global__ __launch_bounds__(256) void norm1t_k(const float* __restrict__ x,
    const float* __restrict__ alpha1, const float* __restrict__ beta1,
    ushort* __restrict__ hn1T){
  __shared__ float tile[32][33];
  int b = blockIdx.z, n0 = blockIdx.x*32, d0 = blockIdx.y*32;
  int tx = threadIdx.x & 31, ty = threadIdx.x >> 5;
  float a = alpha1[d0+tx], be = beta1[d0+tx];
  #pragma unroll
  for (int i=0;i<4;i++){
    int n = n0 + ty + i*8;
    tile[ty+i*8][tx] = (n < Nn) ? fmaf(a, x[((long)b*Nn + n)*Dd + d0 + tx], be) : 0.f;
  }
  __syncthreads();
  #pragma unroll
  for (int i=0;i<4;i++){
    int d = d0 + ty + i*8;
    hn1T[((long)b*Dd + d)*NPAD + n0 + tx] = f2bf(tile[tx][ty+i*8]);
  }
}

// ---------- 128x128 bf16 MFMA tile core ----------
// A rows = output rows, Bt rows = output cols; both [*, ld] with K contiguous.
// Wave w=(tid>>6): wr=w>>1, wc=w&1 -> 64x64 subtile of 4x4 16x16 fragments.
__device__ __forceinline__ void gemm_core(const ushort* __restrict__ Atile, int ldA,
                                          const ushort* __restrict__ Btile, int ldB,
                                          int K, ushort* As, ushort* Bs, f32x4 acc[4][4]){
  const int tid  = threadIdx.x;
  const int lane = tid & 63;
  const int wr   = (tid >> 7) & 1;
  const int wc   = (tid >> 6) & 1;
  const int srow = tid >> 2;          // 0..63
  const int scol = (tid & 3) * 8;     // 0,8,16,24 (bf16 elems)
  const int arow = lane & 15;
  const int koff = (lane >> 4) * 8;
  for (int k0 = 0; k0 < K; k0 += 32){
    // issue global loads early, then fence LDS reuse
    int4 a0 = *(const int4*)(Atile + (long)srow*ldA + k0 + scol);
    int4 a1 = *(const int4*)(Atile + (long)(srow+64)*ldA + k0 + scol);
    int4 b0 = *(const int4*)(Btile + (long)srow*ldB + k0 + scol);
    int4 b1 = *(const int4*)(Btile + (long)(srow+64)*ldB + k0 + scol);
    __syncthreads();
    *(int4*)&As[srow*32 + scol]      = a0;
    *(int4*)&As[(srow+64)*32 + scol] = a1;
    *(int4*)&Bs[srow*32 + scol]      = b0;
    *(int4*)&Bs[(srow+64)*32 + scol] = b1;
    __syncthreads();
    bf16x8 ag[4], bg[4];
    #pragma unroll
    for (int i=0;i<4;i++){
      ag[i] = *(const bf16x8*)&As[(wr*64 + i*16 + arow)*32 + koff];
      bg[i] = *(const bf16x8*)&Bs[(wc*64 + i*16 + arow)*32 + koff];
    }
    #pragma unroll
    for (int i=0;i<4;i++)
      #pragma unroll
      for (int j=0;j<4;j++)
        acc[i][j] = __builtin_amdgcn_mfma_f32_16x16x32_bf16(ag[i], bg[j], acc[i][j], 0, 0, 0);
  }
}

// ---------- GEMM1: token mixing; epilogue writes x1 (f32, in d_out) and hn2 (bf16) ----------
__global__ __launch_bounds__(256) void gemm1_k(const ushort* __restrict__ Wq,
    const ushort* __restrict__ hn1T, const float* __restrict__ x,
    const float* __restrict__ b_attn, const float* __restrict__ gamma1,
    const float* __restrict__ alpha2, const float* __restrict__ beta2,
    float* __restrict__ x1, ushort* __restrict__ hn2){
  __shared__ ushort As[128*32];
  __shared__ ushort Bs[128*32];
  int b = blockIdx.z, mt = blockIdx.y, dt = blockIdx.x;
  f32x4 acc[4][4] = {};
  gemm_core(Wq + mt*128*NPAD, NPAD,
            hn1T + ((long)b*Dd + dt*128)*NPAD, NPAD, NPAD, As, Bs, acc);
  int lane = threadIdx.x & 63;
  int wr = (threadIdx.x >> 7) & 1, wc = (threadIdx.x >> 6) & 1;
  #pragma unroll
  for (int i=0;i<4;i++){
    #pragma unroll
    for (int j=0;j<4;j++){
      int d = dt*128 + wc*64 + j*16 + (lane & 15);
      float g1 = gamma1[d], a2 = alpha2[d], b2v = beta2[d];
      #pragma unroll
      for (int r=0;r<4;r++){
        int m = mt*128 + wr*64 + i*16 + (lane >> 4)*4 + r;
        if (m < Nn){
          long idx = ((long)b*Nn + m)*Dd + d;
          float o = fmaf(g1, acc[i][j][r] + b_attn[m], x[idx]);
          x1[idx]  = o;
          hn2[idx] = f2bf(fmaf(a2, o, b2v));
        }
      }
    }
  }
}

// ---------- GEMM2: h2 = bf16(gelu(hn2 @ W1q^T + b1)) for one token chunk ----------
__global__ __launch_bounds__(256) void gemm2_k(const ushort* __restrict__ hn2,
    const ushort* __restrict__ W1q, const float* __restrict__ b1,
    ushort* __restrict__ h2, int t0){
  __shared__ ushort As[128*32];
  __shared__ ushort Bs[128*32];
  int tt = blockIdx.x, ht = blockIdx.y;
  f32x4 acc[4][4] = {};
  gemm_core(hn2 + ((long)t0 + tt*128)*Dd, Dd, W1q + (long)ht*128*Dd, Dd, Dd, As, Bs, acc);
  int lane = threadIdx.x & 63;
  int wr = (threadIdx.x >> 7) & 1, wc = (threadIdx.x >> 6) & 1;
  #pragma unroll
  for (int i=0;i<4;i++){
    #pragma unroll
    for (int j=0;j<4;j++){
      int h = ht*128 + wc*64 + j*16 + (lane & 15);
      float bias = b1[h];
      #pragma unroll
      for (int r=0;r<4;r++){
        int t = tt*128 + wr*64 + i*16 + (lane >> 4)*4 + r;
        float v = acc[i][j][r] + bias;
        // jax.nn.gelu approximate=True: v*sigmoid(2*0.79788456*(v+0.044715 v^3))
        float u = 0.7978845608028654f * v * fmaf(0.044715f, v*v, 1.f);
        float g = v / (1.f + __expf(-2.f*u));
        h2[(long)t*Hh + h] = f2bf(g);
      }
    }
  }
}

// ---------- GEMM3: out = gamma2*(h2 @ W2q^T + b2) + x1 (x1 lives in d_out) ----------
__global__ __launch_bounds__(256) void gemm3_k(const ushort* __restrict__ h2,
    const ushort* __restrict__ W2q, const float* __restrict__ b2,
    const float* __restrict__ gamma2, float* __restrict__ out, int t0){
  __shared__ ushort As[128*32];
  __shared__ ushort Bs[128*32];
  int tt = blockIdx.x, dt = blockIdx.y;
  f32x4 acc[4][4] = {};
  gemm_core(h2 + (long)tt*128*Hh, Hh, W2q + (long)dt*128*Hh, Hh, Hh, As, Bs, acc);
  int lane = threadIdx.x & 63;
  int wr = (threadIdx.x >> 7) & 1, wc = (threadIdx.x >> 6) & 1;
  #pragma unroll
  for (int i=0;i<4;i++){
    #pragma unroll
    for (int j=0;j<4;j++){
      int d = dt*128 + wc*64 + j*16 + (lane & 15);
      float g2 = gamma2[d], bias = b2[d];
      #pragma unroll
      for (int r=0;r<4;r++){
        long t = (long)t0 + tt*128 + wr*64 + i*16 + (lane >> 4)*4 + r;
        long idx = t*Dd + d;
        out[idx] = fmaf(g2, acc[i][j][r] + bias, out[idx]);  // out holds x1 here
      }
    }
  }
}

extern "C" void kernel_launch(void* const* d_in, const int* in_sizes, int n_in,
                              void* d_out, int out_size, void* d_ws, size_t ws_size,
                              hipStream_t stream){
  const float* x      = (const float*)d_in[0];
  const float* alpha1 = (const float*)d_in[1];
  const float* beta1  = (const float*)d_in[2];
  const float* W_attn = (const float*)d_in[3];
  const float* b_attn = (const float*)d_in[4];
  const float* gamma1 = (const float*)d_in[5];
  const float* alpha2 = (const float*)d_in[6];
  const float* beta2  = (const float*)d_in[7];
  const float* W1     = (const float*)d_in[8];
  const float* b1     = (const float*)d_in[9];
  const float* W2     = (const float*)d_in[10];
  const float* b2     = (const float*)d_in[11];
  const float* gamma2 = (const float*)d_in[12];
  const int*   bits   = (const int*)d_in[13];

  // ws layout (256B aligned), total ~124 MB
  char* ws = (char*)d_ws;
  unsigned* amax = (unsigned*)ws;                    // [3]
  ushort* Wq   = (ushort*)(ws + 256);                // [256][224] bf16
  ushort* W1q  = (ushort*)(ws + 114944);             // [1536][384]
  ushort* W2q  = (ushort*)(ws + 1294592);            // [384][1536]
  ushort* hn1T = (ushort*)(ws + 2474240);            // [256][384][224]
  ushort* hn2  = (ushort*)(ws + 46514432);           // [50176][384]
  ushort* h2   = (ushort*)(ws + 85049600);           // [12544][1536] chunk
  float*  x1   = (float*)d_out;                      // residual staged in d_out

  hipMemsetAsync(amax, 0, 256, stream);
  absmax_k<<<128, 256, 0, stream>>>(W_attn, Nn*Nn, amax + 0);
  absmax_k<<<256, 256, 0, stream>>>(W1, Hh*Dd, amax + 1);
  absmax_k<<<256, 256, 0, stream>>>(W2, Hh*Dd, amax + 2);
  quant_attn_k<<<(MPAD*NPAD)/256, 256, 0, stream>>>(W_attn, amax, bits, Wq);
  quant_k<<<(Hh*Dd)/256, 256, 0, stream>>>(W1, Hh*Dd, amax + 1, bits, W1q);
  quant_k<<<(Hh*Dd)/256, 256, 0, stream>>>(W2, Hh*Dd, amax + 2, bits, W2q);
  norm1t_k<<<dim3(7, 12, Bb), 256, 0, stream>>>(x, alpha1, beta1, hn1T);
  gemm1_k<<<dim3(3, 2, Bb), 256, 0, stream>>>(Wq, hn1T, x, b_attn, gamma1,
                                              alpha2, beta2, x1, hn2);
  for (int c = 0; c < NCHUNK; c++){
    gemm2_k<<<dim3(TCHUNK/128, Hh/128), 256, 0, stream>>>(hn2, W1q, b1, h2, c*TCHUNK);
    gemm3_k<<<dim3(TCHUNK/128, Dd/128), 256, 0, stream>>>(h2, W2q, b2, gamma2,
                                                          (float*)d_out, c*TCHUNK);
  }
}

// Round 2
// 401.533 us; speedup vs baseline: 1.2283x; 1.2283x over previous
//
#include <hip/hip_runtime.h>
#include <hip/hip_bf16.h>
#include <stdint.h>

// Problem dims (fixed by harness)
#define Bb 256
#define Nn 196
#define Dd 384
#define Hh 1536
#define NPAD 224      // patch-dim K padded to 7*32 for MFMA
#define MPAD 256      // Wq row pad to 2*128 tiles
#define TTOT (Bb*Nn)  // 50176 tokens
#define XLD 232       // padded LDS stride for Xs (224+8): breaks bank aliasing

typedef __attribute__((ext_vector_type(8))) __bf16 bf16x8;
typedef __attribute__((ext_vector_type(4))) float f32x4;

// async global->LDS, 16B per lane. LDS dest must be wave-uniform base + lane*16.
#define GLD16(gp, lp) __builtin_amdgcn_global_load_lds( \
    (const __attribute__((address_space(1))) void*)(gp), \
    (__attribute__((address_space(3))) void*)(lp), 16, 0, 0)

__device__ __forceinline__ ushort f2bf(float f){
  union { float f; unsigned u; } v; v.f = f;
  unsigned r = v.u + 0x7FFFu + ((v.u >> 16) & 1u);   // RNE f32->bf16
  return (ushort)(r >> 16);
}

// ---------- absmax reduction over a weight tensor ----------
__global__ void absmax_k(const float* __restrict__ w, int n, unsigned* __restrict__ out){
  float m = 0.f;
  for (int i = blockIdx.x*blockDim.x + threadIdx.x; i < n; i += gridDim.x*blockDim.x)
    m = fmaxf(m, fabsf(w[i]));
  #pragma unroll
  for (int o = 32; o >= 1; o >>= 1) m = fmaxf(m, __shfl_xor(m, o));
  __shared__ float sm[4];
  if ((threadIdx.x & 63) == 0) sm[threadIdx.x >> 6] = m;
  __syncthreads();
  if (threadIdx.x == 0){
    float mm = fmaxf(fmaxf(sm[0], sm[1]), fmaxf(sm[2], sm[3]));
    atomicMax(out, __float_as_uint(mm));   // floats >=0: uint order == float order
  }
}

// ---------- fake-quant W_attn into zero-padded bf16 [MPAD][NPAD] ----------
__global__ void quant_attn_k(const float* __restrict__ W, const unsigned* __restrict__ amax,
                             const int* __restrict__ bitsp, ushort* __restrict__ Wq){
  int idx = blockIdx.x*256 + threadIdx.x;      // grid covers MPAD*NPAD exactly
  int m = idx / NPAD, n = idx - m*NPAD;
  float qmax = (float)((1 << (bitsp[0]-1)) - 1);
  float s = fmaxf(__uint_as_float(amax[0]) / qmax, 1e-8f);
  float v = 0.f;
  if (m < Nn && n < Nn){
    float q = fminf(fmaxf(rintf(W[m*Nn + n] / s), -qmax), qmax);  // rintf = RNE like jnp.round
    v = q * s;
  }
  Wq[idx] = f2bf(v);
}

// ---------- fake-quant a row-major weight to bf16 (same layout) ----------
__global__ void quant_k(const float* __restrict__ W, int n, const unsigned* __restrict__ amax,
                        const int* __restrict__ bitsp, ushort* __restrict__ Wq){
  int idx = blockIdx.x*256 + threadIdx.x;
  if (idx >= n) return;
  float qmax = (float)((1 << (bitsp[0]-1)) - 1);
  float s = fmaxf(__uint_as_float(amax[0]) / qmax, 1e-8f);
  float q = fminf(fmaxf(rintf(W[idx] / s), -qmax), qmax);
  Wq[idx] = f2bf(q * s);
}

// ---------- stage a 128x32 bf16 tile into linear LDS [128][32] via global_load_lds ----------
__device__ __forceinline__ void stage_tile(const ushort* __restrict__ src, long ld, int k0,
                                           ushort* dst){
  const int tid = threadIdx.x;
  const long row = tid >> 2;
  const int  c8  = (tid & 3) * 8;
  GLD16(src + row*ld + k0 + c8,        dst + tid*8);          // rows 0..63
  GLD16(src + (row+64)*ld + k0 + c8,   dst + 2048 + tid*8);   // rows 64..127
}

// ---------- 128x128 bf16 MFMA tile core (m97 structure: gl_lds + 2 barriers/K-step) ----------
__device__ __forceinline__ void gemm_core_gl(const ushort* __restrict__ A, long ldA,
                                             const ushort* __restrict__ B, long ldB,
                                             int K, ushort* As, ushort* Bs, f32x4 acc[4][4]){
  const int tid  = threadIdx.x;
  const int lane = tid & 63;
  const int wr   = (tid >> 7) & 1;
  const int wc   = (tid >> 6) & 1;
  const int arow = lane & 15;
  const int koff = (lane >> 4) * 8;
  for (int k0 = 0; k0 < K; k0 += 32){
    __syncthreads();                 // protect LDS from previous iteration's readers
    stage_tile(A, ldA, k0, As);
    stage_tile(B, ldB, k0, Bs);
    __syncthreads();                 // drains vmcnt before ds_read
    bf16x8 ag[4], bg[4];
    #pragma unroll
    for (int i=0;i<4;i++){
      ag[i] = *(const bf16x8*)&As[(wr*64 + i*16 + arow)*32 + koff];
      bg[i] = *(const bf16x8*)&Bs[(wc*64 + i*16 + arow)*32 + koff];
    }
    #pragma unroll
    for (int i=0;i<4;i++)
      #pragma unroll
      for (int j=0;j<4;j++)
        acc[i][j] = __builtin_amdgcn_mfma_f32_16x16x32_bf16(ag[i], bg[j], acc[i][j], 0, 0, 0);
  }
}

// ---------- GEMM1 fused: norm1 + transpose + token-mix + layerscale/residual + norm2 ----------
// Block (dt, b): computes out rows m=0..195 for d-slice [dt*128, +128).
// Xs[d][n] (bf16, stride XLD) holds normed-x transposed, built in-block.
__global__ __launch_bounds__(256) void gemm1_k(const ushort* __restrict__ Wq,
    const float* __restrict__ x,
    const float* __restrict__ alpha1, const float* __restrict__ beta1,
    const float* __restrict__ b_attn, const float* __restrict__ gamma1,
    const float* __restrict__ alpha2, const float* __restrict__ beta2,
    float* __restrict__ x1, ushort* __restrict__ hn2){
  __shared__ ushort Xs[128*XLD];     // 59392 B
  __shared__ ushort BufAs[8192];     // 16 KB: f32 staging buf, then reused as 8 KB As
  const int tid = threadIdx.x;
  const int b = blockIdx.y, dt = blockIdx.x, d0 = dt*128;

  // ---- build Xs: per pass, 32 n-rows of x[b][n][d0:d0+128] -> normed bf16 transposed ----
  {
    float* buf = (float*)BufAs;      // [32][128] f32, linear (gl_lds needs no padding)
    const int dme = tid & 127;
    const float a1 = alpha1[d0 + dme], be1 = beta1[d0 + dme];
    for (int p = 0; p < 7; p++){
      __syncthreads();
      #pragma unroll
      for (int c = 0; c < 4; c++){
        int nn = p*32 + c*8 + (tid >> 5);
        int ncl = nn < Nn ? nn : Nn - 1;          // clamp (no OOB); zeroed at transpose
        GLD16(x + ((long)b*Nn + ncl)*Dd + d0 + (tid & 31)*4,
              (char*)BufAs + c*4096 + tid*16);
      }
      __syncthreads();
      for (int g = tid >> 7; g < 4; g += 2){      // each thread: 2 groups of 8 n
        int n0 = g*8;
        ushort o[8];
        #pragma unroll
        for (int t = 0; t < 8; t++){
          int na = p*32 + n0 + t;
          float val = (na < Nn) ? fmaf(a1, buf[(n0 + t)*128 + dme], be1) : 0.f;
          o[t] = f2bf(val);
        }
        *(int4*)&Xs[dme*XLD + p*32 + n0] = *(int4*)o;
      }
    }
  }

  // ---- 2 M-tiles of 128 over Wq rows; B = persistent Xs ----
  const int lane = tid & 63;
  const int wr = (tid >> 7) & 1, wc = (tid >> 6) & 1;
  const int arow = lane & 15, koff = (lane >> 4)*8;
  ushort* As = BufAs;                // 8 KB reuse
  for (int mt = 0; mt < 2; mt++){
    f32x4 acc[4][4] = {};
    const ushort* Wt = Wq + (long)mt*128*NPAD;
    for (int k0 = 0; k0 < NPAD; k0 += 32){
      __syncthreads();
      stage_tile(Wt, NPAD, k0, As);
      __syncthreads();
      bf16x8 ag[4], bg[4];
      #pragma unroll
      for (int i=0;i<4;i++){
        ag[i] = *(const bf16x8*)&As[(wr*64 + i*16 + arow)*32 + koff];
        bg[i] = *(const bf16x8*)&Xs[(wc*64 + i*16 + arow)*XLD + k0 + koff];
      }
      #pragma unroll
      for (int i=0;i<4;i++)
        #pragma unroll
        for (int j=0;j<4;j++)
          acc[i][j] = __builtin_amdgcn_mfma_f32_16x16x32_bf16(ag[i], bg[j], acc[i][j], 0, 0, 0);
    }
    // epilogue for this M-tile
    #pragma unroll
    for (int i=0;i<4;i++){
      #pragma unroll
      for (int j=0;j<4;j++){
        int d = d0 + wc*64 + j*16 + (lane & 15);
        float g1 = gamma1[d], a2 = alpha2[d], b2v = beta2[d];
        #pragma unroll
        for (int r=0;r<4;r++){
          int m = mt*128 + wr*64 + i*16 + (lane >> 4)*4 + r;
          if (m < Nn){
            long idx = ((long)b*Nn + m)*Dd + d;
            float o = fmaf(g1, acc[i][j][r] + b_attn[m], x[idx]);  // x re-read: L2-warm
            x1[idx]  = o;
            hn2[idx] = f2bf(fmaf(a2, o, b2v));
          }
        }
      }
    }
  }
}

// ---------- GEMM2: h2 = bf16(gelu(hn2 @ W1q^T + b1)) for one token chunk ----------
__global__ __launch_bounds__(256) void gemm2_k(const ushort* __restrict__ hn2,
    const ushort* __restrict__ W1q, const float* __restrict__ b1,
    ushort* __restrict__ h2, int t0){
  __shared__ ushort As[4096];
  __shared__ ushort Bs[4096];
  int ht = blockIdx.x, tt = blockIdx.y;     // x = ht so tt-groups share A-tile in L2
  f32x4 acc[4][4] = {};
  gemm_core_gl(hn2 + ((long)t0 + tt*128)*Dd, Dd, W1q + (long)ht*128*Dd, Dd, Dd, As, Bs, acc);
  int lane = threadIdx.x & 63;
  int wr = (threadIdx.x >> 7) & 1, wc = (threadIdx.x >> 6) & 1;
  #pragma unroll
  for (int i=0;i<4;i++){
    #pragma unroll
    for (int j=0;j<4;j++){
      int h = ht*128 + wc*64 + j*16 + (lane & 15);
      float bias = b1[h];
      #pragma unroll
      for (int r=0;r<4;r++){
        int t = tt*128 + wr*64 + i*16 + (lane >> 4)*4 + r;
        float v = acc[i][j][r] + bias;
        // jax.nn.gelu approximate=True: v*sigmoid(2*0.79788456*(v+0.044715 v^3))
        float u = 0.7978845608028654f * v * fmaf(0.044715f, v*v, 1.f);
        float g = v / (1.f + __expf(-2.f*u));
        h2[(long)t*Hh + h] = f2bf(g);
      }
    }
  }
}

// ---------- GEMM3: out = gamma2*(h2 @ W2q^T + b2) + x1 (x1 lives in d_out) ----------
__global__ __launch_bounds__(256) void gemm3_k(const ushort* __restrict__ h2,
    const ushort* __restrict__ W2q, const float* __restrict__ b2,
    const float* __restrict__ gamma2, float* __restrict__ out, int t0){
  __shared__ ushort As[4096];
  __shared__ ushort Bs[4096];
  int dt = blockIdx.x, tt = blockIdx.y;
  f32x4 acc[4][4] = {};
  gemm_core_gl(h2 + (long)tt*128*Hh, Hh, W2q + (long)dt*128*Hh, Hh, Hh, As, Bs, acc);
  int lane = threadIdx.x & 63;
  int wr = (threadIdx.x >> 7) & 1, wc = (threadIdx.x >> 6) & 1;
  #pragma unroll
  for (int i=0;i<4;i++){
    #pragma unroll
    for (int j=0;j<4;j++){
      int d = dt*128 + wc*64 + j*16 + (lane & 15);
      float g2 = gamma2[d], bias = b2[d];
      #pragma unroll
      for (int r=0;r<4;r++){
        long t = (long)t0 + tt*128 + wr*64 + i*16 + (lane >> 4)*4 + r;
        long idx = t*Dd + d;
        out[idx] = fmaf(g2, acc[i][j][r] + bias, out[idx]);  // out holds x1 here
      }
    }
  }
}

extern "C" void kernel_launch(void* const* d_in, const int* in_sizes, int n_in,
                              void* d_out, int out_size, void* d_ws, size_t ws_size,
                              hipStream_t stream){
  const float* x      = (const float*)d_in[0];
  const float* alpha1 = (const float*)d_in[1];
  const float* beta1  = (const float*)d_in[2];
  const float* W_attn = (const float*)d_in[3];
  const float* b_attn = (const float*)d_in[4];
  const float* gamma1 = (const float*)d_in[5];
  const float* alpha2 = (const float*)d_in[6];
  const float* beta2  = (const float*)d_in[7];
  const float* W1     = (const float*)d_in[8];
  const float* b1     = (const float*)d_in[9];
  const float* W2     = (const float*)d_in[10];
  const float* b2     = (const float*)d_in[11];
  const float* gamma2 = (const float*)d_in[12];
  const int*   bits   = (const int*)d_in[13];

  // ws layout (256B aligned)
  char* ws = (char*)d_ws;
  unsigned* amax = (unsigned*)ws;                    // [3]
  ushort* Wq   = (ushort*)(ws + 256);                // [256][224] bf16
  ushort* W1q  = (ushort*)(ws + 114944);             // [1536][384]
  ushort* W2q  = (ushort*)(ws + 1294592);            // [384][1536]
  ushort* hn2  = (ushort*)(ws + 2474240);            // [50176][384]
  ushort* h2   = (ushort*)(ws + 41009408);           // [TCHUNK][1536]
  float*  x1   = (float*)d_out;                      // residual staged in d_out

  // pick largest chunking that fits ws: fixed end = 41,009,408 B; h2 chunk = TC*1536*2
  const size_t fixed_end = 41009408ull;
  int nchunk;
  if      (ws_size >= fixed_end + 154140672ull) nchunk = 1;
  else if (ws_size >= fixed_end +  77070336ull) nchunk = 2;
  else                                          nchunk = 4;
  const int TC = TTOT / nchunk;

  hipMemsetAsync(amax, 0, 256, stream);
  absmax_k<<<128, 256, 0, stream>>>(W_attn, Nn*Nn, amax + 0);
  absmax_k<<<256, 256, 0, stream>>>(W1, Hh*Dd, amax + 1);
  absmax_k<<<256, 256, 0, stream>>>(W2, Hh*Dd, amax + 2);
  quant_attn_k<<<(MPAD*NPAD)/256, 256, 0, stream>>>(W_attn, amax, bits, Wq);
  quant_k<<<(Hh*Dd)/256, 256, 0, stream>>>(W1, Hh*Dd, amax + 1, bits, W1q);
  quant_k<<<(Hh*Dd)/256, 256, 0, stream>>>(W2, Hh*Dd, amax + 2, bits, W2q);
  gemm1_k<<<dim3(3, Bb), 256, 0, stream>>>(Wq, x, alpha1, beta1, b_attn, gamma1,
                                           alpha2, beta2, x1, hn2);
  for (int c = 0; c < nchunk; c++){
    gemm2_k<<<dim3(Hh/128, TC/128), 256, 0, stream>>>(hn2, W1q, b1, h2, c*TC);
    gemm3_k<<<dim3(Dd/128, TC/128), 256, 0, stream>>>(h2, W2q, b2, gamma2,
                                                      (float*)d_out, c*TC);
  }
}